// Round 1
// baseline (968.882 us; speedup 1.0000x reference)
//
#include <hip/hip_runtime.h>
#include <math.h>

// ---------------------------------------------------------------------------
// GCN: h1 = relu(dstn * S(ew * srcn*(X@W1))) ; h2 = relu(dstn * S(ew * srcn*([h1,X]@W2)))
// out = l2normalize(h2)   where S = segment_sum over edges (src -> dst)
// ---------------------------------------------------------------------------

__global__ void deg_kernel(const int* __restrict__ src, const int* __restrict__ dst,
                           float* __restrict__ degs, float* __restrict__ degd, int E) {
    int i = blockIdx.x * blockDim.x + threadIdx.x;
    if (i < E) {
        atomicAdd(&degs[src[i]], 1.0f);
        atomicAdd(&degd[dst[i]], 1.0f);
    }
}

__global__ void norm_kernel(const float* __restrict__ degs, const float* __restrict__ degd,
                            float* __restrict__ srcn, float* __restrict__ dstn, int N) {
    int i = blockIdx.x * blockDim.x + threadIdx.x;
    if (i < N) {
        srcn[i] = rsqrtf(fmaxf(degs[i], 1.0f));
        dstn[i] = rsqrtf(fmaxf(degd[i], 1.0f));
    }
}

// xp[n][j] = srcn[n] * sum_k X[n][k] * W1[k][j]    (X: [N,32], W1: [32,64])
__global__ void proj1_kernel(const float* __restrict__ X, const float* __restrict__ W1,
                             const float* __restrict__ srcn, float* __restrict__ xp, int N) {
    __shared__ float w[32 * 64];
    for (int i = threadIdx.x; i < 32 * 64; i += blockDim.x) w[i] = W1[i];
    __syncthreads();
    int j = threadIdx.x & 63;
    int n = blockIdx.x * 4 + (threadIdx.x >> 6);
    if (n >= N) return;
    const float* x = X + (size_t)n * 32;
    float acc = 0.0f;
#pragma unroll
    for (int k = 0; k < 32; ++k) acc += x[k] * w[k * 64 + j];
    xp[(size_t)n * 64 + j] = acc * srcn[n];
}

// xp[n][j] = srcn[n] * ( sum_k h[n][k]*W2[k][j] + sum_k X[n][k]*W2[64+k][j] )
__global__ void proj2_kernel(const float* __restrict__ h, const float* __restrict__ X,
                             const float* __restrict__ W2, const float* __restrict__ srcn,
                             float* __restrict__ xp, int N) {
    __shared__ float w[96 * 64];
    for (int i = threadIdx.x; i < 96 * 64; i += blockDim.x) w[i] = W2[i];
    __syncthreads();
    int j = threadIdx.x & 63;
    int n = blockIdx.x * 4 + (threadIdx.x >> 6);
    if (n >= N) return;
    const float* hr = h + (size_t)n * 64;
    const float* xr = X + (size_t)n * 32;
    float acc = 0.0f;
#pragma unroll
    for (int k = 0; k < 64; ++k) acc += hr[k] * w[k * 64 + j];
#pragma unroll
    for (int k = 0; k < 32; ++k) acc += xr[k] * w[(64 + k) * 64 + j];
    xp[(size_t)n * 64 + j] = acc * srcn[n];
}

// acc[dst[e]][f] += xp[src[e]][f] * ew[e]   (one wave handles one edge; lane = feature)
__global__ void scatter_kernel(const int* __restrict__ src, const int* __restrict__ dst,
                               const float* __restrict__ ew, const float* __restrict__ xp,
                               float* __restrict__ acc, int E) {
    int total = E * 64;
    int stride = gridDim.x * blockDim.x;
    for (int i = blockIdx.x * blockDim.x + threadIdx.x; i < total; i += stride) {
        int e = i >> 6;
        int f = i & 63;
        int s = src[e];
        int d = dst[e];
        float v = xp[(size_t)s * 64 + f] * ew[e];
        atomicAdd(&acc[(size_t)d * 64 + f], v);
    }
}

// in-place: h[n][j] = relu(h[n][j]*dstn[n] + b[j])
__global__ void relu_bias_kernel(float* __restrict__ h, const float* __restrict__ dstn,
                                 const float* __restrict__ b, int N) {
    int i = blockIdx.x * blockDim.x + threadIdx.x;
    if (i < N * 64) {
        int n = i >> 6;
        int j = i & 63;
        h[i] = fmaxf(h[i] * dstn[n] + b[j], 0.0f);
    }
}

// in-place: v = relu(out*dstn + b); out = v / max(||v||2, 1e-12)   (one wave per row)
__global__ void finalize_kernel(float* __restrict__ out, const float* __restrict__ dstn,
                                const float* __restrict__ b, int N) {
    int i = blockIdx.x * blockDim.x + threadIdx.x;
    int n = i >> 6;
    int f = i & 63;
    if (n >= N) return;
    float v = fmaxf(out[(size_t)n * 64 + f] * dstn[n] + b[f], 0.0f);
    float s = v * v;
#pragma unroll
    for (int off = 32; off >= 1; off >>= 1) s += __shfl_xor(s, off, 64);
    out[(size_t)n * 64 + f] = v / fmaxf(sqrtf(s), 1e-12f);
}

extern "C" void kernel_launch(void* const* d_in, const int* in_sizes, int n_in,
                              void* d_out, int out_size, void* d_ws, size_t ws_size,
                              hipStream_t stream) {
    const float* X   = (const float*)d_in[0];   // [N,32]
    const float* ew  = (const float*)d_in[1];   // [E,1]
    const int*   src = (const int*)d_in[2];     // [E]
    const int*   dst = (const int*)d_in[3];     // [E]
    const float* W1  = (const float*)d_in[4];   // [32,64]
    const float* b1  = (const float*)d_in[5];   // [64]
    const float* W2  = (const float*)d_in[6];   // [96,64]
    const float* b2  = (const float*)d_in[7];   // [64]

    const int N = in_sizes[0] / 32;
    const int E = in_sizes[2];

    float* ws   = (float*)d_ws;
    float* degs = ws;               // [N]
    float* degd = ws + N;           // [N]
    float* srcn = ws + 2 * (size_t)N;  // [N]
    float* dstn = ws + 3 * (size_t)N;  // [N]
    float* xp   = ws + 4 * (size_t)N;  // [N,64]
    float* out  = (float*)d_out;       // [N,64] doubles as scatter accumulator

    hipMemsetAsync(degs, 0, 2 * (size_t)N * sizeof(float), stream);
    hipMemsetAsync(out, 0, (size_t)N * 64 * sizeof(float), stream);

    deg_kernel<<<(E + 255) / 256, 256, 0, stream>>>(src, dst, degs, degd, E);
    norm_kernel<<<(N + 255) / 256, 256, 0, stream>>>(degs, degd, srcn, dstn, N);

    // ---- layer 1 ----
    proj1_kernel<<<(N + 3) / 4, 256, 0, stream>>>(X, W1, srcn, xp, N);
    scatter_kernel<<<2048, 256, 0, stream>>>(src, dst, ew, xp, out, E);
    relu_bias_kernel<<<(N * 64 + 255) / 256, 256, 0, stream>>>(out, dstn, b1, N);

    // ---- layer 2 ----  (h lives in `out`; xp buffer reused for projection)
    proj2_kernel<<<(N + 3) / 4, 256, 0, stream>>>(out, X, W2, srcn, xp, N);
    hipMemsetAsync(out, 0, (size_t)N * 64 * sizeof(float), stream);
    scatter_kernel<<<2048, 256, 0, stream>>>(src, dst, ew, xp, out, E);
    finalize_kernel<<<(N * 64 + 255) / 256, 256, 0, stream>>>(out, dstn, b2, N);
}

// Round 2
// 532.493 us; speedup vs baseline: 1.8195x; 1.8195x over previous
//
#include <hip/hip_runtime.h>
#include <math.h>

// ---------------------------------------------------------------------------
// GCN via on-the-fly dst-CSR + gather segment-sum (no feature-level atomics).
// h1 = relu(dstn * S(ew * srcn*(X@W1)) + b1)
// h2 = relu(dstn * S(ew * srcn*([h1,X]@W2)) + b2) ; out = l2norm(h2)
// ---------------------------------------------------------------------------

#define SCAN_BS 256
#define SCAN_ITEMS 4
#define SCAN_CHUNK (SCAN_BS * SCAN_ITEMS)

__global__ void deg_kernel_i(const int* __restrict__ src, const int* __restrict__ dst,
                             int* __restrict__ degs, int* __restrict__ degd, int E) {
    int i = blockIdx.x * blockDim.x + threadIdx.x;
    if (i < E) {
        atomicAdd(&degs[src[i]], 1);
        atomicAdd(&degd[dst[i]], 1);
    }
}

// per-block sums of degd chunks
__global__ void scan_partial(const int* __restrict__ degd, int* __restrict__ bsum, int N) {
    __shared__ int sdata[SCAN_BS];
    int t = threadIdx.x;
    int base = blockIdx.x * SCAN_CHUNK + t * SCAN_ITEMS;
    int s = 0;
#pragma unroll
    for (int k = 0; k < SCAN_ITEMS; ++k) {
        int idx = base + k;
        s += (idx < N) ? degd[idx] : 0;
    }
    sdata[t] = s;
    __syncthreads();
    for (int off = SCAN_BS / 2; off > 0; off >>= 1) {
        if (t < off) sdata[t] += sdata[t + off];
        __syncthreads();
    }
    if (t == 0) bsum[blockIdx.x] = sdata[0];
}

// exclusive scan of block sums (single block, 64 threads, handles NB>64 via carry)
__global__ void scan_bsums(int* __restrict__ bsum, int NB) {
    int carry = 0;
    for (int base = 0; base < NB; base += 64) {
        int l = base + (int)threadIdx.x;
        int v = (l < NB) ? bsum[l] : 0;
        int inc = v;
#pragma unroll
        for (int off = 1; off < 64; off <<= 1) {
            int tv = __shfl_up(inc, off, 64);
            if ((int)threadIdx.x >= off) inc += tv;
        }
        if (l < NB) bsum[l] = carry + inc - v;  // exclusive
        carry += __shfl(inc, 63, 64);
    }
}

// final scan: offsets/cursor + degree norms
__global__ void scan_final(const int* __restrict__ degs, const int* __restrict__ degd,
                           const int* __restrict__ bsum, int* __restrict__ offsets,
                           int* __restrict__ cursor, float* __restrict__ srcn,
                           float* __restrict__ dstn, int N, int E) {
    __shared__ int sdata[SCAN_BS];
    int t = threadIdx.x;
    int base = blockIdx.x * SCAN_CHUNK + t * SCAN_ITEMS;
    int loc[SCAN_ITEMS];
    int s = 0;
#pragma unroll
    for (int k = 0; k < SCAN_ITEMS; ++k) {
        int idx = base + k;
        loc[k] = (idx < N) ? degd[idx] : 0;
        s += loc[k];
    }
    sdata[t] = s;
    __syncthreads();
    // Hillis-Steele inclusive scan over thread sums
    for (int off = 1; off < SCAN_BS; off <<= 1) {
        int v = (t >= off) ? sdata[t - off] : 0;
        __syncthreads();
        sdata[t] += v;
        __syncthreads();
    }
    int excl = sdata[t] - s + bsum[blockIdx.x];
#pragma unroll
    for (int k = 0; k < SCAN_ITEMS; ++k) {
        int idx = base + k;
        if (idx < N) {
            offsets[idx] = excl;
            cursor[idx] = excl;
            dstn[idx] = rsqrtf(fmaxf((float)loc[k], 1.0f));
            srcn[idx] = rsqrtf(fmaxf((float)degs[idx], 1.0f));
            if (idx == N - 1) offsets[N] = excl + loc[k];
        }
        excl += loc[k];
    }
}

// place packed (src, ew) into CSR slots grouped by dst
__global__ void fill_kernel(const int* __restrict__ src, const int* __restrict__ dst,
                            const float* __restrict__ ew, int* __restrict__ cursor,
                            int2* __restrict__ edata, int E) {
    int e = blockIdx.x * blockDim.x + threadIdx.x;
    if (e < E) {
        int d = dst[e];
        int pos = atomicAdd(&cursor[d], 1);
        edata[pos] = make_int2(src[e], __float_as_int(ew[e]));
    }
}

// xp[n][j] = srcn[n] * sum_k X[n][k] * W1[k][j]    (X: [N,32], W1: [32,64])
__global__ void proj1_kernel(const float* __restrict__ X, const float* __restrict__ W1,
                             const float* __restrict__ srcn, float* __restrict__ xp, int N) {
    __shared__ float w[32 * 64];
    for (int i = threadIdx.x; i < 32 * 64; i += blockDim.x) w[i] = W1[i];
    __syncthreads();
    int j = threadIdx.x & 63;
    int n = blockIdx.x * 4 + (threadIdx.x >> 6);
    if (n >= N) return;
    const float* x = X + (size_t)n * 32;
    float acc = 0.0f;
#pragma unroll
    for (int k = 0; k < 32; ++k) acc += x[k] * w[k * 64 + j];
    xp[(size_t)n * 64 + j] = acc * srcn[n];
}

// xp[n][j] = srcn[n] * ( sum_k h[n][k]*W2[k][j] + sum_k X[n][k]*W2[64+k][j] )
__global__ void proj2_kernel(const float* __restrict__ h, const float* __restrict__ X,
                             const float* __restrict__ W2, const float* __restrict__ srcn,
                             float* __restrict__ xp, int N) {
    __shared__ float w[96 * 64];
    for (int i = threadIdx.x; i < 96 * 64; i += blockDim.x) w[i] = W2[i];
    __syncthreads();
    int j = threadIdx.x & 63;
    int n = blockIdx.x * 4 + (threadIdx.x >> 6);
    if (n >= N) return;
    const float* hr = h + (size_t)n * 64;
    const float* xr = X + (size_t)n * 32;
    float acc = 0.0f;
#pragma unroll
    for (int k = 0; k < 64; ++k) acc += hr[k] * w[k * 64 + j];
#pragma unroll
    for (int k = 0; k < 32; ++k) acc += xr[k] * w[(64 + k) * 64 + j];
    xp[(size_t)n * 64 + j] = acc * srcn[n];
}

// one wave per node; lane = feature. Register accumulate, single row write.
template <bool FINAL>
__global__ void gather_kernel(const int* __restrict__ offsets, const int2* __restrict__ edata,
                              const float* __restrict__ xp, const float* __restrict__ dstn,
                              const float* __restrict__ b, float* __restrict__ out, int N) {
    int lane = threadIdx.x & 63;
    int n = blockIdx.x * (blockDim.x >> 6) + (threadIdx.x >> 6);
    if (n >= N) return;
    int beg = offsets[n];
    int end = offsets[n + 1];
    float acc = 0.0f;
    int p = beg;
    for (; p + 1 < end; p += 2) {
        int2 e0 = edata[p];
        int2 e1 = edata[p + 1];
        float v0 = xp[(size_t)e0.x * 64 + lane];
        float v1 = xp[(size_t)e1.x * 64 + lane];
        acc += v0 * __int_as_float(e0.y);
        acc += v1 * __int_as_float(e1.y);
    }
    if (p < end) {
        int2 e0 = edata[p];
        acc += xp[(size_t)e0.x * 64 + lane] * __int_as_float(e0.y);
    }
    float v = fmaxf(acc * dstn[n] + b[lane], 0.0f);
    if (FINAL) {
        float s = v * v;
#pragma unroll
        for (int off = 32; off >= 1; off >>= 1) s += __shfl_xor(s, off, 64);
        v = v / fmaxf(sqrtf(s), 1e-12f);
    }
    out[(size_t)n * 64 + lane] = v;
}

// ---------------- fallback path (atomic scatter, round-1) ----------------

__global__ void norm_kernel_i(const int* __restrict__ degs, const int* __restrict__ degd,
                              float* __restrict__ srcn, float* __restrict__ dstn, int N) {
    int i = blockIdx.x * blockDim.x + threadIdx.x;
    if (i < N) {
        srcn[i] = rsqrtf(fmaxf((float)degs[i], 1.0f));
        dstn[i] = rsqrtf(fmaxf((float)degd[i], 1.0f));
    }
}

__global__ void scatter_kernel(const int* __restrict__ src, const int* __restrict__ dst,
                               const float* __restrict__ ew, const float* __restrict__ xp,
                               float* __restrict__ acc, int E) {
    int total = E * 64;
    int stride = gridDim.x * blockDim.x;
    for (int i = blockIdx.x * blockDim.x + threadIdx.x; i < total; i += stride) {
        int e = i >> 6;
        int f = i & 63;
        int s = src[e];
        int d = dst[e];
        float v = xp[(size_t)s * 64 + f] * ew[e];
        atomicAdd(&acc[(size_t)d * 64 + f], v);
    }
}

__global__ void relu_bias_kernel(float* __restrict__ h, const float* __restrict__ dstn,
                                 const float* __restrict__ b, int N) {
    int i = blockIdx.x * blockDim.x + threadIdx.x;
    if (i < N * 64) {
        int n = i >> 6;
        int j = i & 63;
        h[i] = fmaxf(h[i] * dstn[n] + b[j], 0.0f);
    }
}

__global__ void finalize_kernel(float* __restrict__ out, const float* __restrict__ dstn,
                                const float* __restrict__ b, int N) {
    int i = blockIdx.x * blockDim.x + threadIdx.x;
    int n = i >> 6;
    int f = i & 63;
    if (n >= N) return;
    float v = fmaxf(out[(size_t)n * 64 + f] * dstn[n] + b[f], 0.0f);
    float s = v * v;
#pragma unroll
    for (int off = 32; off >= 1; off >>= 1) s += __shfl_xor(s, off, 64);
    out[(size_t)n * 64 + f] = v / fmaxf(sqrtf(s), 1e-12f);
}

// ---------------------------------------------------------------------------

extern "C" void kernel_launch(void* const* d_in, const int* in_sizes, int n_in,
                              void* d_out, int out_size, void* d_ws, size_t ws_size,
                              hipStream_t stream) {
    const float* X   = (const float*)d_in[0];   // [N,32]
    const float* ew  = (const float*)d_in[1];   // [E,1]
    const int*   src = (const int*)d_in[2];     // [E]
    const int*   dst = (const int*)d_in[3];     // [E]
    const float* W1  = (const float*)d_in[4];   // [32,64]
    const float* b1  = (const float*)d_in[5];   // [64]
    const float* W2  = (const float*)d_in[6];   // [96,64]
    const float* b2  = (const float*)d_in[7];   // [64]

    const int N = in_sizes[0] / 32;
    const int E = in_sizes[2];
    const int NB = (N + SCAN_CHUNK - 1) / SCAN_CHUNK;

    float* out = (float*)d_out;
    char* wsb = (char*)d_ws;

    // CSR-path workspace requirement (4-byte units):
    // xp[64N] + edata[2E] + degs[N] + degd[N] + srcn[N] + dstn[N]
    // + offsets[N+1] + cursor[N] + bsum[NB]
    size_t need = ((size_t)64 * N + 2 * (size_t)E + 5 * (size_t)N + 1 + (size_t)NB + 16) * 4;

    if (ws_size >= need) {
        size_t o = 0;
        float* xp      = (float*)(wsb + o); o += (size_t)64 * N * 4;
        int2*  edata   = (int2*)(wsb + o);  o += (size_t)2 * E * 4;
        int*   degs_i  = (int*)(wsb + o);   o += (size_t)N * 4;
        int*   degd_i  = (int*)(wsb + o);   o += (size_t)N * 4;
        float* srcn    = (float*)(wsb + o); o += (size_t)N * 4;
        float* dstn    = (float*)(wsb + o); o += (size_t)N * 4;
        int*   offsets = (int*)(wsb + o);   o += ((size_t)N + 1) * 4;
        int*   cursor  = (int*)(wsb + o);   o += (size_t)N * 4;
        int*   bsum    = (int*)(wsb + o);   o += (size_t)NB * 4;

        hipMemsetAsync(degs_i, 0, 2 * (size_t)N * 4, stream);  // degs_i + degd_i
        deg_kernel_i<<<(E + 255) / 256, 256, 0, stream>>>(src, dst, degs_i, degd_i, E);
        scan_partial<<<NB, SCAN_BS, 0, stream>>>(degd_i, bsum, N);
        scan_bsums<<<1, 64, 0, stream>>>(bsum, NB);
        scan_final<<<NB, SCAN_BS, 0, stream>>>(degs_i, degd_i, bsum, offsets, cursor,
                                               srcn, dstn, N, E);
        fill_kernel<<<(E + 255) / 256, 256, 0, stream>>>(src, dst, ew, cursor, edata, E);

        // layer 1: project, gather-sum, fused relu+bias+dstn -> h (stored in d_out)
        proj1_kernel<<<(N + 3) / 4, 256, 0, stream>>>(X, W1, srcn, xp, N);
        gather_kernel<false><<<(N + 3) / 4, 256, 0, stream>>>(offsets, edata, xp, dstn, b1, out, N);

        // layer 2: project concat(h,X), gather-sum, fused relu+bias+dstn+l2norm -> d_out
        proj2_kernel<<<(N + 3) / 4, 256, 0, stream>>>(out, X, W2, srcn, xp, N);
        gather_kernel<true><<<(N + 3) / 4, 256, 0, stream>>>(offsets, edata, xp, dstn, b2, out, N);
    } else {
        // fallback: round-1 atomic-scatter pipeline (smaller ws footprint)
        float* ws   = (float*)d_ws;
        int*   degs = (int*)ws;                 // [N]
        int*   degd = (int*)(ws + N);           // [N]
        float* srcn = ws + 2 * (size_t)N;       // [N]
        float* dstn = ws + 3 * (size_t)N;       // [N]
        float* xp   = ws + 4 * (size_t)N;       // [N,64]

        hipMemsetAsync(degs, 0, 2 * (size_t)N * sizeof(float), stream);
        hipMemsetAsync(out, 0, (size_t)N * 64 * sizeof(float), stream);

        deg_kernel_i<<<(E + 255) / 256, 256, 0, stream>>>(src, dst, degs, degd, E);
        norm_kernel_i<<<(N + 255) / 256, 256, 0, stream>>>(degs, degd, srcn, dstn, N);

        proj1_kernel<<<(N + 3) / 4, 256, 0, stream>>>(X, W1, srcn, xp, N);
        scatter_kernel<<<2048, 256, 0, stream>>>(src, dst, ew, xp, out, E);
        relu_bias_kernel<<<(N * 64 + 255) / 256, 256, 0, stream>>>(out, dstn, b1, N);

        proj2_kernel<<<(N + 3) / 4, 256, 0, stream>>>(out, X, W2, srcn, xp, N);
        hipMemsetAsync(out, 0, (size_t)N * 64 * sizeof(float), stream);
        scatter_kernel<<<2048, 256, 0, stream>>>(src, dst, ew, xp, out, E);
        finalize_kernel<<<(N * 64 + 255) / 256, 256, 0, stream>>>(out, dstn, b2, N);
    }
}

// Round 3
// 343.758 us; speedup vs baseline: 2.8185x; 1.5490x over previous
//
#include <hip/hip_runtime.h>
#include <math.h>

// ---------------------------------------------------------------------------
// GCN via dst-CSR built with LDS histograms (zero global atomics).
// h1 = relu(dstn * S(ew * srcn*(X@W1)) + b1)
// h2 = relu(dstn * S(ew * srcn*([h1,X]@W2)) + b2) ; out = l2norm(h2)
// ---------------------------------------------------------------------------

#define SD 128           // dst histogram slices (also fill blocks)
#define SS 16            // src histogram slices
#define HIST_BS 1024
#define MAX_LDS_BYTES 131072

#define SCAN_BS 256
#define SCAN_ITEMS 4
#define SCAN_CHUNK (SCAN_BS * SCAN_ITEMS)

// ---- histogram: per-slice packed u16 counts over all N bins (LDS) ----------
__global__ void hist_kernel(const int* __restrict__ src, const int* __restrict__ dst,
                            unsigned* __restrict__ partial_d, unsigned* __restrict__ partial_s,
                            int E, int NW, int sliceD, int sliceS) {
    extern __shared__ unsigned h[];
    for (int i = threadIdx.x; i < NW; i += blockDim.x) h[i] = 0u;
    __syncthreads();
    const int* idx;
    unsigned* out;
    int beg, end;
    if ((int)blockIdx.x < SD) {
        int s = blockIdx.x;
        idx = dst; out = partial_d + (size_t)s * NW;
        beg = s * sliceD; end = min(beg + sliceD, E);
    } else {
        int s = blockIdx.x - SD;
        idx = src; out = partial_s + (size_t)s * NW;
        beg = s * sliceS; end = min(beg + sliceS, E);
    }
    for (int e = beg + (int)threadIdx.x; e < end; e += blockDim.x) {
        int v = idx[e];
        atomicAdd(&h[v >> 1], (v & 1) ? 0x10000u : 1u);
    }
    __syncthreads();
    for (int i = threadIdx.x; i < NW; i += blockDim.x) out[i] = h[i];
}

// ---- reduce: totals + norms; transform partial_d in place into per-slice
//      exclusive ranks (packed u16) along the slice axis -----------------------
__global__ void reduce_kernel(unsigned* __restrict__ partial_d,
                              const unsigned* __restrict__ partial_s,
                              int* __restrict__ degd_total, float* __restrict__ srcn,
                              float* __restrict__ dstn, int N, int NW) {
    int w = blockIdx.x * blockDim.x + threadIdx.x;
    if (w >= NW) return;
    unsigned rlo = 0, rhi = 0;
    for (int s = 0; s < SD; ++s) {
        size_t i = (size_t)s * NW + w;
        unsigned c = partial_d[i];
        partial_d[i] = rlo | (rhi << 16);   // exclusive prefix (rank base)
        rlo += c & 0xffffu;
        rhi += c >> 16;
    }
    unsigned slo = 0, shi = 0;
    for (int s = 0; s < SS; ++s) {
        unsigned c = partial_s[(size_t)s * NW + w];
        slo += c & 0xffffu;
        shi += c >> 16;
    }
    int b0 = 2 * w, b1 = 2 * w + 1;
    degd_total[b0] = (int)rlo;
    dstn[b0] = rsqrtf(fmaxf((float)rlo, 1.0f));
    srcn[b0] = rsqrtf(fmaxf((float)slo, 1.0f));
    if (b1 < N) {
        degd_total[b1] = (int)rhi;
        dstn[b1] = rsqrtf(fmaxf((float)rhi, 1.0f));
        srcn[b1] = rsqrtf(fmaxf((float)shi, 1.0f));
    }
}

// ---- 3-kernel exclusive scan over degd_total -> offsets ---------------------
__global__ void scan_partial(const int* __restrict__ deg, int* __restrict__ bsum, int N) {
    __shared__ int sdata[SCAN_BS];
    int t = threadIdx.x;
    int base = blockIdx.x * SCAN_CHUNK + t * SCAN_ITEMS;
    int s = 0;
#pragma unroll
    for (int k = 0; k < SCAN_ITEMS; ++k) {
        int idx = base + k;
        s += (idx < N) ? deg[idx] : 0;
    }
    sdata[t] = s;
    __syncthreads();
    for (int off = SCAN_BS / 2; off > 0; off >>= 1) {
        if (t < off) sdata[t] += sdata[t + off];
        __syncthreads();
    }
    if (t == 0) bsum[blockIdx.x] = sdata[0];
}

__global__ void scan_bsums(int* __restrict__ bsum, int NB) {
    int carry = 0;
    for (int base = 0; base < NB; base += 64) {
        int l = base + (int)threadIdx.x;
        int v = (l < NB) ? bsum[l] : 0;
        int inc = v;
#pragma unroll
        for (int off = 1; off < 64; off <<= 1) {
            int tv = __shfl_up(inc, off, 64);
            if ((int)threadIdx.x >= off) inc += tv;
        }
        if (l < NB) bsum[l] = carry + inc - v;  // exclusive
        carry += __shfl(inc, 63, 64);
    }
}

__global__ void scan_final(const int* __restrict__ deg, const int* __restrict__ bsum,
                           int* __restrict__ offsets, int N) {
    __shared__ int sdata[SCAN_BS];
    int t = threadIdx.x;
    int base = blockIdx.x * SCAN_CHUNK + t * SCAN_ITEMS;
    int loc[SCAN_ITEMS];
    int s = 0;
#pragma unroll
    for (int k = 0; k < SCAN_ITEMS; ++k) {
        int idx = base + k;
        loc[k] = (idx < N) ? deg[idx] : 0;
        s += loc[k];
    }
    sdata[t] = s;
    __syncthreads();
    for (int off = 1; off < SCAN_BS; off <<= 1) {
        int v = (t >= off) ? sdata[t - off] : 0;
        __syncthreads();
        sdata[t] += v;
        __syncthreads();
    }
    int excl = sdata[t] - s + bsum[blockIdx.x];
#pragma unroll
    for (int k = 0; k < SCAN_ITEMS; ++k) {
        int idx = base + k;
        if (idx < N) {
            offsets[idx] = excl;
            if (idx == N - 1) offsets[N] = excl + loc[k];
        }
        excl += loc[k];
    }
}

// ---- CSR fill without global atomics: LDS rank counters ---------------------
__global__ void fill2_kernel(const int* __restrict__ src, const int* __restrict__ dst,
                             const float* __restrict__ ew, const int* __restrict__ offsets,
                             const unsigned* __restrict__ rel, int2* __restrict__ edata,
                             int E, int NW, int sliceD) {
    extern __shared__ unsigned cnt[];
    for (int i = threadIdx.x; i < NW; i += blockDim.x) cnt[i] = 0u;
    __syncthreads();
    int s = blockIdx.x;
    int beg = s * sliceD, end = min(beg + sliceD, E);
    const unsigned* relS = rel + (size_t)s * NW;
    for (int e = beg + (int)threadIdx.x; e < end; e += blockDim.x) {
        int d = dst[e];
        unsigned old = atomicAdd(&cnt[d >> 1], (d & 1) ? 0x10000u : 1u);
        unsigned rank = (d & 1) ? (old >> 16) : (old & 0xffffu);
        unsigned r = relS[d >> 1];
        unsigned rr = (d & 1) ? (r >> 16) : (r & 0xffffu);
        int pos = offsets[d] + (int)rr + (int)rank;
        edata[pos] = make_int2(src[e], __float_as_int(ew[e]));
    }
}

// ---- projections -------------------------------------------------------------
__global__ void proj1_kernel(const float* __restrict__ X, const float* __restrict__ W1,
                             const float* __restrict__ srcn, float* __restrict__ xp, int N) {
    __shared__ float w[32 * 64];
    for (int i = threadIdx.x; i < 32 * 64; i += blockDim.x) w[i] = W1[i];
    __syncthreads();
    int j = threadIdx.x & 63;
    int n = blockIdx.x * 4 + (threadIdx.x >> 6);
    if (n >= N) return;
    const float* x = X + (size_t)n * 32;
    float acc = 0.0f;
#pragma unroll
    for (int k = 0; k < 32; ++k) acc += x[k] * w[k * 64 + j];
    xp[(size_t)n * 64 + j] = acc * srcn[n];
}

__global__ void proj2_kernel(const float* __restrict__ h, const float* __restrict__ X,
                             const float* __restrict__ W2, const float* __restrict__ srcn,
                             float* __restrict__ xp, int N) {
    __shared__ float w[96 * 64];
    for (int i = threadIdx.x; i < 96 * 64; i += blockDim.x) w[i] = W2[i];
    __syncthreads();
    int j = threadIdx.x & 63;
    int n = blockIdx.x * 4 + (threadIdx.x >> 6);
    if (n >= N) return;
    const float* hr = h + (size_t)n * 64;
    const float* xr = X + (size_t)n * 32;
    float acc = 0.0f;
#pragma unroll
    for (int k = 0; k < 64; ++k) acc += hr[k] * w[k * 64 + j];
#pragma unroll
    for (int k = 0; k < 32; ++k) acc += xr[k] * w[(64 + k) * 64 + j];
    xp[(size_t)n * 64 + j] = acc * srcn[n];
}

// ---- gather segment-sum: one wave per node, lane = feature -------------------
template <bool FINAL>
__global__ void gather_kernel(const int* __restrict__ offsets, const int2* __restrict__ edata,
                              const float* __restrict__ xp, const float* __restrict__ dstn,
                              const float* __restrict__ b, float* __restrict__ out, int N) {
    int lane = threadIdx.x & 63;
    int n = blockIdx.x * (blockDim.x >> 6) + (threadIdx.x >> 6);
    if (n >= N) return;
    int beg = offsets[n];
    int end = offsets[n + 1];
    float acc0 = 0.0f, acc1 = 0.0f;
    int p = beg;
    for (; p + 3 < end; p += 4) {
        int2 e0 = edata[p];
        int2 e1 = edata[p + 1];
        int2 e2 = edata[p + 2];
        int2 e3 = edata[p + 3];
        float v0 = xp[(size_t)e0.x * 64 + lane];
        float v1 = xp[(size_t)e1.x * 64 + lane];
        float v2 = xp[(size_t)e2.x * 64 + lane];
        float v3 = xp[(size_t)e3.x * 64 + lane];
        acc0 = fmaf(v0, __int_as_float(e0.y), acc0);
        acc1 = fmaf(v1, __int_as_float(e1.y), acc1);
        acc0 = fmaf(v2, __int_as_float(e2.y), acc0);
        acc1 = fmaf(v3, __int_as_float(e3.y), acc1);
    }
    for (; p < end; ++p) {
        int2 e0 = edata[p];
        acc0 = fmaf(xp[(size_t)e0.x * 64 + lane], __int_as_float(e0.y), acc0);
    }
    float v = fmaxf((acc0 + acc1) * dstn[n] + b[lane], 0.0f);
    if (FINAL) {
        float s = v * v;
#pragma unroll
        for (int off = 32; off >= 1; off >>= 1) s += __shfl_xor(s, off, 64);
        v = v / fmaxf(sqrtf(s), 1e-12f);
    }
    out[(size_t)n * 64 + lane] = v;
}

// ---------------- fallback path (atomic scatter) ------------------------------
__global__ void deg_kernel_i(const int* __restrict__ src, const int* __restrict__ dst,
                             int* __restrict__ degs, int* __restrict__ degd, int E) {
    int i = blockIdx.x * blockDim.x + threadIdx.x;
    if (i < E) {
        atomicAdd(&degs[src[i]], 1);
        atomicAdd(&degd[dst[i]], 1);
    }
}

__global__ void norm_kernel_i(const int* __restrict__ degs, const int* __restrict__ degd,
                              float* __restrict__ srcn, float* __restrict__ dstn, int N) {
    int i = blockIdx.x * blockDim.x + threadIdx.x;
    if (i < N) {
        srcn[i] = rsqrtf(fmaxf((float)degs[i], 1.0f));
        dstn[i] = rsqrtf(fmaxf((float)degd[i], 1.0f));
    }
}

__global__ void scatter_kernel(const int* __restrict__ src, const int* __restrict__ dst,
                               const float* __restrict__ ew, const float* __restrict__ xp,
                               float* __restrict__ acc, int E) {
    int total = E * 64;
    int stride = gridDim.x * blockDim.x;
    for (int i = blockIdx.x * blockDim.x + threadIdx.x; i < total; i += stride) {
        int e = i >> 6;
        int f = i & 63;
        int s = src[e];
        int d = dst[e];
        float v = xp[(size_t)s * 64 + f] * ew[e];
        atomicAdd(&acc[(size_t)d * 64 + f], v);
    }
}

__global__ void relu_bias_kernel(float* __restrict__ h, const float* __restrict__ dstn,
                                 const float* __restrict__ b, int N) {
    int i = blockIdx.x * blockDim.x + threadIdx.x;
    if (i < N * 64) {
        int n = i >> 6;
        int j = i & 63;
        h[i] = fmaxf(h[i] * dstn[n] + b[j], 0.0f);
    }
}

__global__ void finalize_kernel(float* __restrict__ out, const float* __restrict__ dstn,
                                const float* __restrict__ b, int N) {
    int i = blockIdx.x * blockDim.x + threadIdx.x;
    int n = i >> 6;
    int f = i & 63;
    if (n >= N) return;
    float v = fmaxf(out[(size_t)n * 64 + f] * dstn[n] + b[f], 0.0f);
    float s = v * v;
#pragma unroll
    for (int off = 32; off >= 1; off >>= 1) s += __shfl_xor(s, off, 64);
    out[(size_t)n * 64 + f] = v / fmaxf(sqrtf(s), 1e-12f);
}

// ---------------------------------------------------------------------------

extern "C" void kernel_launch(void* const* d_in, const int* in_sizes, int n_in,
                              void* d_out, int out_size, void* d_ws, size_t ws_size,
                              hipStream_t stream) {
    const float* X   = (const float*)d_in[0];   // [N,32]
    const float* ew  = (const float*)d_in[1];   // [E,1]
    const int*   src = (const int*)d_in[2];     // [E]
    const int*   dst = (const int*)d_in[3];     // [E]
    const float* W1  = (const float*)d_in[4];   // [32,64]
    const float* b1  = (const float*)d_in[5];   // [64]
    const float* W2  = (const float*)d_in[6];   // [96,64]
    const float* b2  = (const float*)d_in[7];   // [64]

    const int N = in_sizes[0] / 32;
    const int E = in_sizes[2];
    const int NB = (N + SCAN_CHUNK - 1) / SCAN_CHUNK;
    const int NW = (N + 1) / 2;                 // packed u16 pairs
    const int sliceD = (E + SD - 1) / SD;
    const int sliceS = (E + SS - 1) / SS;

    float* out = (float*)d_out;
    char* wsb = (char*)d_ws;

    // layout with aliasing:
    //   region A: partial_d[SD*NW u32]  -> later xp[N*64 f32]   (xp written after fill)
    //   region B: partial_s[SS*NW u32] overlapping edata[E int2] (partial_s dead pre-fill)
    size_t o = 0;
    auto alloc = [&](size_t bytes) { size_t p = o; o += (bytes + 255) & ~(size_t)255; return p; };
    size_t offA    = alloc((((size_t)SD * NW * 4) > ((size_t)N * 64 * 4))
                               ? ((size_t)SD * NW * 4) : ((size_t)N * 64 * 4));
    size_t offB    = alloc((((size_t)E * 8) > ((size_t)SS * NW * 4))
                               ? ((size_t)E * 8) : ((size_t)SS * NW * 4));
    size_t offDegd = alloc((size_t)N * 4);
    size_t offSrcn = alloc((size_t)N * 4);
    size_t offDstn = alloc((size_t)N * 4);
    size_t offOff  = alloc(((size_t)N + 1) * 4);
    size_t offBsum = alloc((size_t)NB * 4);
    size_t need = o;

    bool ldsOK = ((size_t)NW * 4 <= MAX_LDS_BYTES);
    // histogram packing requires per-node degree < 65536 within any slice; guaranteed
    // when total degree < 65536 -- true for this workload (avg deg = 32).

    if (ws_size >= need && ldsOK) {
        unsigned* partial_d = (unsigned*)(wsb + offA);
        float*    xp        = (float*)(wsb + offA);
        unsigned* partial_s = (unsigned*)(wsb + offB);
        int2*     edata     = (int2*)(wsb + offB);
        int*      degd_tot  = (int*)(wsb + offDegd);
        float*    srcn      = (float*)(wsb + offSrcn);
        float*    dstn      = (float*)(wsb + offDstn);
        int*      offsets   = (int*)(wsb + offOff);
        int*      bsum      = (int*)(wsb + offBsum);

        hist_kernel<<<SD + SS, HIST_BS, (size_t)NW * 4, stream>>>(
            src, dst, partial_d, partial_s, E, NW, sliceD, sliceS);
        reduce_kernel<<<(NW + 255) / 256, 256, 0, stream>>>(
            partial_d, partial_s, degd_tot, srcn, dstn, N, NW);
        scan_partial<<<NB, SCAN_BS, 0, stream>>>(degd_tot, bsum, N);
        scan_bsums<<<1, 64, 0, stream>>>(bsum, NB);
        scan_final<<<NB, SCAN_BS, 0, stream>>>(degd_tot, bsum, offsets, N);
        fill2_kernel<<<SD, HIST_BS, (size_t)NW * 4, stream>>>(
            src, dst, ew, offsets, partial_d, edata, E, NW, sliceD);

        // layer 1
        proj1_kernel<<<(N + 3) / 4, 256, 0, stream>>>(X, W1, srcn, xp, N);
        gather_kernel<false><<<(N + 3) / 4, 256, 0, stream>>>(offsets, edata, xp, dstn, b1, out, N);
        // layer 2
        proj2_kernel<<<(N + 3) / 4, 256, 0, stream>>>(out, X, W2, srcn, xp, N);
        gather_kernel<true><<<(N + 3) / 4, 256, 0, stream>>>(offsets, edata, xp, dstn, b2, out, N);
    } else {
        // fallback: atomic-scatter pipeline
        float* ws   = (float*)d_ws;
        int*   degs = (int*)ws;
        int*   degd = (int*)(ws + N);
        float* srcn = ws + 2 * (size_t)N;
        float* dstn = ws + 3 * (size_t)N;
        float* xp   = ws + 4 * (size_t)N;

        hipMemsetAsync(degs, 0, 2 * (size_t)N * sizeof(float), stream);
        hipMemsetAsync(out, 0, (size_t)N * 64 * sizeof(float), stream);

        deg_kernel_i<<<(E + 255) / 256, 256, 0, stream>>>(src, dst, degs, degd, E);
        norm_kernel_i<<<(N + 255) / 256, 256, 0, stream>>>(degs, degd, srcn, dstn, N);

        proj1_kernel<<<(N + 3) / 4, 256, 0, stream>>>(X, W1, srcn, xp, N);
        scatter_kernel<<<2048, 256, 0, stream>>>(src, dst, ew, xp, out, E);
        relu_bias_kernel<<<(N * 64 + 255) / 256, 256, 0, stream>>>(out, dstn, b1, N);

        proj2_kernel<<<(N + 3) / 4, 256, 0, stream>>>(out, X, W2, srcn, xp, N);
        hipMemsetAsync(out, 0, (size_t)N * 64 * sizeof(float), stream);
        scatter_kernel<<<2048, 256, 0, stream>>>(src, dst, ew, xp, out, E);
        finalize_kernel<<<(N * 64 + 255) / 256, 256, 0, stream>>>(out, dstn, b2, N);
    }
}